// Round 6
// baseline (482.017 us; speedup 1.0000x reference)
//
#include <hip/hip_runtime.h>

// BootstrapEnsemble: M=100 MLPs (16 -> 128 -> 4x(128x128) -> {mu, log sigma}),
// shared batch N=16384.
//  1) cvt_weights: one-shot fp32->bf16 (linear, row-major) of x/W1/Wh/Wmu/Wsig
//     into d_ws.
//  2) ens_mlp: fused MFMA MLP with ZERO barriers. Block = (model, 256 rows),
//     4 waves; each wave owns a private 64-row n-band and computes ALL 128
//     k_out for it -> layer-to-layer dataflow never crosses waves -> the LDS
//     h-tile is wave-private scratch and no __syncthreads() exists anywhere.
//     Waves free-run at different phases so MFMA of one hides L2/LDS latency
//     of another. W fragments stream from L2-hot global with a manual 2-bank
//     per-kc prefetch pipeline. Swapped-operand mfma_16x16x32_bf16; bias in
//     the MFMA C operand. LDS XOR swizzle col ^= (row&15)<<3. Per-wave
//     s_waitcnt lgkmcnt(0) fences order in-wave LDS write->read (no barrier).

typedef float  f32x4  __attribute__((ext_vector_type(4)));
typedef __bf16 bf16x4 __attribute__((ext_vector_type(4)));
typedef __bf16 bf16x8 __attribute__((ext_vector_type(8)));

union BF8 { bf16x8 v; unsigned int ui[4]; };
union BF4 { bf16x4 v; uint2 u2; };

#define MODELS 100
#define NPT    16384
#define HDIM   128
#define SG_OFF (MODELS * NPT)

// d_ws layout (bf16 element offsets), all row-major / linear
#define XB_OFF   0                       // x:    16384 x 16
#define W1B_OFF  262144                  // W1:   100 x 128 x 16
#define WHB_OFF  466944                  // Wh:   100 x 4 x 128 x 128
#define WMU_OFF  7020544                 // Wmu:  100 x 128
#define WSG_OFF  7033344                 // Wsig: 100 x 128

#define GTOT 880768                      // total 8-elem groups

__global__ __launch_bounds__(256) void cvt_weights(
    const float* __restrict__ x,   const float* __restrict__ W1,
    const float* __restrict__ Wh,  const float* __restrict__ Wmu,
    const float* __restrict__ Wsg, unsigned short* __restrict__ ws)
{
  int gid = blockIdx.x * 256 + threadIdx.x;
  if (gid >= GTOT) return;
  const float* src;
  unsigned int dst;
  if (gid < 32768)       { src = x   + gid * 8;                 dst = XB_OFF  + gid * 8; }
  else if (gid < 58368)  { int q = gid - 32768;  src = W1  + q * 8;          dst = W1B_OFF + q * 8; }
  else if (gid < 877568) { int q = gid - 58368;  src = Wh  + (size_t)q * 8;  dst = WHB_OFF + q * 8; }
  else if (gid < 879168) { int q = gid - 877568; src = Wmu + q * 8;          dst = WMU_OFF + q * 8; }
  else                   { int q = gid - 879168; src = Wsg + q * 8;          dst = WSG_OFF + q * 8; }
  f32x4 a = *(const f32x4*)src;
  f32x4 b = *(const f32x4*)(src + 4);
  BF4 lo, hi;
  lo.v = __builtin_convertvector(a, bf16x4);
  hi.v = __builtin_convertvector(b, bf16x4);
  uint4 u; u.x = lo.u2.x; u.y = lo.u2.y; u.z = hi.u2.x; u.w = hi.u2.y;
  *(uint4*)&ws[dst] = u;
}

__device__ __forceinline__ void load_af(BF8 (&dst)[8], const unsigned short* whm,
                                        int c, int g, int kc) {
#pragma unroll
  for (int kt = 0; kt < 8; ++kt)
    dst[kt].v = *(const bf16x8*)&whm[(kt * 16 + c) * HDIM + kc * 32 + g * 8];
}

__device__ __forceinline__ void do_kc(f32x4 (&acc)[8][4], const BF8 (&af)[8],
                                      const unsigned short* hband,
                                      int c, int g, int cs, int kc) {
  BF8 bfv[4];
#pragma unroll
  for (int nt = 0; nt < 4; ++nt)
    bfv[nt].v = *(const bf16x8*)&hband[(nt * 16 + c) * HDIM + ((kc * 32 + g * 8) ^ cs)];
#pragma unroll
  for (int kt = 0; kt < 8; ++kt)
#pragma unroll
    for (int nt = 0; nt < 4; ++nt)
      acc[kt][nt] = __builtin_amdgcn_mfma_f32_16x16x32_bf16(af[kt].v, bfv[nt].v, acc[kt][nt], 0, 0, 0);
}

__global__ __launch_bounds__(256, 2) void ens_mlp(
    const unsigned short* __restrict__ ws,
    const float* __restrict__ b1,  const float* __restrict__ bh,
    const float* __restrict__ bmu, const float* __restrict__ bsg,
    float* __restrict__ out)
{
  __shared__ unsigned short hb[256 * HDIM]; // 4 wave-PRIVATE 64-row bands, 64 KB

  // XCD-chunked bijective swizzle: 6400 blocks = 8 XCDs * 800
  const int bid = blockIdx.x;
  const int swz = (bid & 7) * 800 + (bid >> 3);
  const int m   = swz >> 6;            // model 0..99
  const int n0  = (swz & 63) << 8;     // 256-row chunk base

  const int t    = threadIdx.x;
  const int lane = t & 63;
  const int wv   = t >> 6;     // wave 0..3
  const int c    = lane & 15;  // frag row / D col (n)
  const int g    = lane >> 4;  // frag k-group / D row group
  const int cs   = c << 3;     // xor swizzle ((row&15)<<3)

  const int nb = n0 + wv * 64;                    // global n base of this wave
  unsigned short* hband = hb + (wv * 64) * HDIM;  // private LDS band

  f32x4 acc[8][4];   // [kt = k_out tile 0..7][nt = n tile 0..3]

  // ---------------- layer 1 (K=16 zero-padded to 32) -----------------------
  {
    const unsigned short* W1m = ws + W1B_OFF + m * (HDIM * 16);
    const unsigned short* xp  = ws + XB_OFF;
    BF8 a1[8], xb[4];
#pragma unroll
    for (int kt = 0; kt < 8; ++kt) {
      if (g < 2) {
        a1[kt].v = *(const bf16x8*)&W1m[(kt * 16 + c) * 16 + g * 8];
      } else {
        a1[kt].ui[0] = 0u; a1[kt].ui[1] = 0u; a1[kt].ui[2] = 0u; a1[kt].ui[3] = 0u;
      }
    }
#pragma unroll
    for (int nt = 0; nt < 4; ++nt) {
      if (g < 2) {
        xb[nt].v = *(const bf16x8*)&xp[(nb + nt * 16 + c) * 16 + g * 8];
      } else {
        xb[nt].ui[0] = 0u; xb[nt].ui[1] = 0u; xb[nt].ui[2] = 0u; xb[nt].ui[3] = 0u;
      }
    }
    {
      f32x4 bs;
#pragma unroll
      for (int kt = 0; kt < 8; ++kt) {
        bs = *(const f32x4*)(b1 + m * HDIM + kt * 16 + g * 4);
#pragma unroll
        for (int nt = 0; nt < 4; ++nt)
          acc[kt][nt] = __builtin_amdgcn_mfma_f32_16x16x32_bf16(a1[kt].v, xb[nt].v, bs, 0, 0, 0);
      }
    }
    // epilogue: relu + cvt -> private band
#pragma unroll
    for (int kt = 0; kt < 8; ++kt) {
      int col = (kt * 16 + g * 4) ^ cs;
#pragma unroll
      for (int nt = 0; nt < 4; ++nt) {
        int row = nt * 16 + c;
        f32x4 v = __builtin_elementwise_max(acc[kt][nt], f32x4{0.f, 0.f, 0.f, 0.f});
        BF4 b; b.v = __builtin_convertvector(v, bf16x4);
        *(uint2*)&hband[row * HDIM + col] = b.u2;
      }
    }
  }

  // ---------------- 4 hidden layers, barrier-free --------------------------
  for (int i = 0; i < 4; ++i) {
    const unsigned short* whm = ws + WHB_OFF + (size_t)(m * 4 + i) * (HDIM * HDIM);

    // acc <- bias
    {
      f32x4 bs;
#pragma unroll
      for (int kt = 0; kt < 8; ++kt) {
        bs = *(const f32x4*)(bh + m * 512 + i * HDIM + kt * 16 + g * 4);
#pragma unroll
        for (int nt = 0; nt < 4; ++nt)
          acc[kt][nt] = bs;
      }
    }

    BF8 afA[8], afB[8];
    load_af(afA, whm, c, g, 0);
    load_af(afB, whm, c, g, 1);

    // in-wave fence: previous epilogue's LDS writes complete before reads
    asm volatile("s_waitcnt lgkmcnt(0)" ::: "memory");

    do_kc(acc, afA, hband, c, g, cs, 0);
    load_af(afA, whm, c, g, 2);
    do_kc(acc, afB, hband, c, g, cs, 1);
    load_af(afB, whm, c, g, 3);
    do_kc(acc, afA, hband, c, g, cs, 2);
    do_kc(acc, afB, hband, c, g, cs, 3);

    // in-wave fence: all band reads done before overwrite
    asm volatile("s_waitcnt lgkmcnt(0)" ::: "memory");

    // epilogue: relu + cvt, write band in place
#pragma unroll
    for (int kt = 0; kt < 8; ++kt) {
      int col = (kt * 16 + g * 4) ^ cs;
#pragma unroll
      for (int nt = 0; nt < 4; ++nt) {
        int row = nt * 16 + c;
        f32x4 v = __builtin_elementwise_max(acc[kt][nt], f32x4{0.f, 0.f, 0.f, 0.f});
        BF4 b; b.v = __builtin_convertvector(v, bf16x4);
        *(uint2*)&hband[row * HDIM + col] = b.u2;
      }
    }
  }

  // ---------------- heads: mu (D row 0) and log-sigma (D row 1) ------------
  {
    float bm  = bmu[m];
    float bsv = bsg[m];
    f32x4 acc2[4];
#pragma unroll
    for (int nt = 0; nt < 4; ++nt) {
      acc2[nt] = f32x4{0.f, 0.f, 0.f, 0.f};
      acc2[nt][0] = bm;
      acc2[nt][1] = bsv;
    }
    asm volatile("s_waitcnt lgkmcnt(0)" ::: "memory");
#pragma unroll
    for (int kc = 0; kc < 4; ++kc) {
      BF8 hw;
      if (c < 2) {
        const unsigned short* wp = ws + (c == 0 ? WMU_OFF : WSG_OFF) + m * HDIM + kc * 32 + g * 8;
        hw.v = *(const bf16x8*)wp;
      } else {
        hw.ui[0] = 0u; hw.ui[1] = 0u; hw.ui[2] = 0u; hw.ui[3] = 0u;
      }
#pragma unroll
      for (int nt = 0; nt < 4; ++nt) {
        BF8 hf;
        hf.v = *(const bf16x8*)&hband[(nt * 16 + c) * HDIM + ((kc * 32 + g * 8) ^ cs)];
        acc2[nt] = __builtin_amdgcn_mfma_f32_16x16x32_bf16(hw.v, hf.v, acc2[nt], 0, 0, 0);
      }
    }
    if (g == 0) {
#pragma unroll
      for (int nt = 0; nt < 4; ++nt) {
        int n = nb + nt * 16 + c;
        out[m * NPT + n]          = acc2[nt][0];
        out[SG_OFF + m * NPT + n] = expf(acc2[nt][1]);
      }
    }
  }
}

extern "C" void kernel_launch(void* const* d_in, const int* in_sizes, int n_in,
                              void* d_out, int out_size, void* d_ws, size_t ws_size,
                              hipStream_t stream) {
  const float* x   = (const float*)d_in[0];
  const float* W1  = (const float*)d_in[1];
  const float* b1  = (const float*)d_in[2];
  const float* Wh  = (const float*)d_in[3];
  const float* bh  = (const float*)d_in[4];
  const float* Wmu = (const float*)d_in[5];
  const float* bmu = (const float*)d_in[6];
  const float* Wsg = (const float*)d_in[7];
  const float* bsg = (const float*)d_in[8];
  unsigned short* ws = (unsigned short*)d_ws;
  (void)in_sizes; (void)n_in; (void)out_size; (void)ws_size;

  cvt_weights<<<(GTOT + 255) / 256, 256, 0, stream>>>(x, W1, Wh, Wmu, Wsg, ws);
  ens_mlp<<<6400, 256, 0, stream>>>(ws, b1, bh, bmu, bsg, (float*)d_out);
}

// Round 7
// 291.872 us; speedup vs baseline: 1.6515x; 1.6515x over previous
//
#include <hip/hip_runtime.h>

// BootstrapEnsemble: M=100 MLPs (16 -> 128 -> 4x(128x128) -> {mu, log sigma}),
// shared batch N=16384.
//  1) cvt_weights: one-shot fp32->bf16 (linear, row-major) of x/W1/Wh/Wmu/Wsig
//     into d_ws.
//  2) ens_mlp: fused MFMA MLP (R3 skeleton: block = model x 256 rows, 4 waves
//     2x2, swapped-operand mfma_16x16x32_bf16, bias in C operand, LDS XOR
//     swizzle col ^= (row&15)<<3). R7 changes:
//       - double-banked af[]: layer i+1's weight fragments are loaded from
//         L2-hot global at the TOP of layer i (latency hidden under MFMAs).
//       - subtile-split accumulator: s=0 compute -> barrier -> s=0 epilogue
//         -> s=1 compute -> barrier -> s=1 epilogue. Legal by row-disjointness
//         (s=0 writes rows 0..127; s=1 reads rows 128..255). acc live-set
//         halves to 64 regs, paying for the 64-reg prefetch bank (no spill).

typedef float  f32x4  __attribute__((ext_vector_type(4)));
typedef __bf16 bf16x4 __attribute__((ext_vector_type(4)));
typedef __bf16 bf16x8 __attribute__((ext_vector_type(8)));

union BF8 { bf16x8 v; unsigned int ui[4]; };
union BF4 { bf16x4 v; uint2 u2; };

#define MODELS 100
#define NPT    16384
#define HDIM   128
#define SG_OFF (MODELS * NPT)

// d_ws layout (bf16 element offsets), all row-major / linear
#define XB_OFF   0                       // x:    16384 x 16
#define W1B_OFF  262144                  // W1:   100 x 128 x 16
#define WHB_OFF  466944                  // Wh:   100 x 4 x 128 x 128
#define WMU_OFF  7020544                 // Wmu:  100 x 128
#define WSG_OFF  7033344                 // Wsig: 100 x 128

#define GTOT 880768                      // total 8-elem groups

__global__ __launch_bounds__(256) void cvt_weights(
    const float* __restrict__ x,   const float* __restrict__ W1,
    const float* __restrict__ Wh,  const float* __restrict__ Wmu,
    const float* __restrict__ Wsg, unsigned short* __restrict__ ws)
{
  int gid = blockIdx.x * 256 + threadIdx.x;
  if (gid >= GTOT) return;
  const float* src;
  unsigned int dst;
  if (gid < 32768)       { src = x   + gid * 8;                 dst = XB_OFF  + gid * 8; }
  else if (gid < 58368)  { int q = gid - 32768;  src = W1  + q * 8;          dst = W1B_OFF + q * 8; }
  else if (gid < 877568) { int q = gid - 58368;  src = Wh  + (size_t)q * 8;  dst = WHB_OFF + q * 8; }
  else if (gid < 879168) { int q = gid - 877568; src = Wmu + q * 8;          dst = WMU_OFF + q * 8; }
  else                   { int q = gid - 879168; src = Wsg + q * 8;          dst = WSG_OFF + q * 8; }
  f32x4 a = *(const f32x4*)src;
  f32x4 b = *(const f32x4*)(src + 4);
  BF4 lo, hi;
  lo.v = __builtin_convertvector(a, bf16x4);
  hi.v = __builtin_convertvector(b, bf16x4);
  uint4 u; u.x = lo.u2.x; u.y = lo.u2.y; u.z = hi.u2.x; u.w = hi.u2.y;
  *(uint4*)&ws[dst] = u;
}

__global__ __launch_bounds__(256, 2) void ens_mlp(
    const unsigned short* __restrict__ ws,
    const float* __restrict__ b1,  const float* __restrict__ bh,
    const float* __restrict__ bmu, const float* __restrict__ bsg,
    float* __restrict__ out)
{
  __shared__ unsigned short hbuf[256 * HDIM]; // [n 0..255][h 0..127] bf16, swizzled

  // XCD-chunked bijective swizzle: 6400 blocks = 8 XCDs * 800
  const int bid = blockIdx.x;
  const int swz = (bid & 7) * 800 + (bid >> 3);
  const int m   = swz >> 6;            // model 0..99
  const int n0  = (swz & 63) << 8;     // 256-row chunk base

  const int t    = threadIdx.x;
  const int lane = t & 63;
  const int wv   = t >> 6;     // wave 0..3
  const int wk   = wv & 1;     // k_out half
  const int wn   = wv >> 1;    // n half
  const int c    = lane & 15;  // frag row (A: k_out, B: n) / D col (n)
  const int g    = lane >> 4;  // frag k-group / D row group
  const int cs   = c << 3;     // xor swizzle ((row&15)<<3)

  const f32x4 zf = {0.0f, 0.0f, 0.0f, 0.0f};

  f32x4 acc[4][4];      // [kt][nt] -- one subtile live at a time
  BF8   afb[2][4][4];   // double-banked W fragments [bank][kt][kc]

  const unsigned short* whbase = ws + WHB_OFF + (size_t)(m * 4) * (HDIM * HDIM);

  // ---- issue layer-0 hidden-weight loads FIRST (in flight during layer 1) --
  #pragma unroll
  for (int kt = 0; kt < 4; ++kt)
    #pragma unroll
    for (int kc = 0; kc < 4; ++kc)
      afb[0][kt][kc].v = *(const bf16x8*)&whbase[(wk * 64 + kt * 16 + c) * HDIM + kc * 32 + g * 8];

  // ---------------- layer 1 (K=16 zero-padded to 32) -----------------------
  {
    const unsigned short* W1m = ws + W1B_OFF + m * (HDIM * 16);
    const unsigned short* xbp = ws + XB_OFF;
    BF8 a1[4];
    #pragma unroll
    for (int kt = 0; kt < 4; ++kt) {
      if (g < 2) {
        a1[kt].v = *(const bf16x8*)&W1m[(wk * 64 + kt * 16 + c) * 16 + g * 8];
      } else {
        a1[kt].ui[0] = 0u; a1[kt].ui[1] = 0u; a1[kt].ui[2] = 0u; a1[kt].ui[3] = 0u;
      }
    }
    f32x4 bs[4];
    #pragma unroll
    for (int kt = 0; kt < 4; ++kt)
      bs[kt] = *(const f32x4*)(b1 + m * HDIM + (wk * 4 + kt) * 16 + g * 4);

    #pragma unroll
    for (int s = 0; s < 2; ++s) {
      BF8 xb[4];
      #pragma unroll
      for (int nt = 0; nt < 4; ++nt) {
        if (g < 2) {
          xb[nt].v = *(const bf16x8*)&xbp[(n0 + s * 128 + wn * 64 + nt * 16 + c) * 16 + g * 8];
        } else {
          xb[nt].ui[0] = 0u; xb[nt].ui[1] = 0u; xb[nt].ui[2] = 0u; xb[nt].ui[3] = 0u;
        }
      }
      #pragma unroll
      for (int kt = 0; kt < 4; ++kt)
        #pragma unroll
        for (int nt = 0; nt < 4; ++nt)
          acc[kt][nt] = __builtin_amdgcn_mfma_f32_16x16x32_bf16(a1[kt].v, xb[nt].v, bs[kt], 0, 0, 0);
      // epilogue: relu + cvt -> hbuf (first writes; no barrier needed before)
      #pragma unroll
      for (int kt = 0; kt < 4; ++kt) {
        int col = ((wk * 4 + kt) * 16 + g * 4) ^ cs;
        #pragma unroll
        for (int nt = 0; nt < 4; ++nt) {
          int row = s * 128 + wn * 64 + nt * 16 + c;
          f32x4 v = __builtin_elementwise_max(acc[kt][nt], zf);
          BF4 b; b.v = __builtin_convertvector(v, bf16x4);
          *(uint2*)&hbuf[row * HDIM + col] = b.u2;
        }
      }
    }
  }
  __syncthreads();

  // ---------------- 4 hidden layers ----------------------------------------
  #pragma unroll
  for (int i = 0; i < 4; ++i) {
    const int cur = i & 1;
    const int nxt = cur ^ 1;

    // prefetch next layer's W fragments into the other bank (hidden under MFMAs)
    if (i < 3) {
      const unsigned short* whn = whbase + (size_t)(i + 1) * (HDIM * HDIM);
      #pragma unroll
      for (int kt = 0; kt < 4; ++kt)
        #pragma unroll
        for (int kc = 0; kc < 4; ++kc)
          afb[nxt][kt][kc].v = *(const bf16x8*)&whn[(wk * 64 + kt * 16 + c) * HDIM + kc * 32 + g * 8];
    }

    f32x4 bs[4];
    #pragma unroll
    for (int kt = 0; kt < 4; ++kt)
      bs[kt] = *(const f32x4*)(bh + m * 512 + i * HDIM + (wk * 4 + kt) * 16 + g * 4);

    // ---- s = 0: compute rows 0..127 ----
    #pragma unroll
    for (int kt = 0; kt < 4; ++kt)
      #pragma unroll
      for (int nt = 0; nt < 4; ++nt)
        acc[kt][nt] = bs[kt];
    #pragma unroll
    for (int kc = 0; kc < 4; ++kc) {
      BF8 bf[4];
      #pragma unroll
      for (int nt = 0; nt < 4; ++nt)
        bf[nt].v = *(const bf16x8*)&hbuf[(wn * 64 + nt * 16 + c) * HDIM + ((kc * 32 + g * 8) ^ cs)];
      #pragma unroll
      for (int kt = 0; kt < 4; ++kt)
        #pragma unroll
        for (int nt = 0; nt < 4; ++nt)
          acc[kt][nt] = __builtin_amdgcn_mfma_f32_16x16x32_bf16(afb[cur][kt][kc].v, bf[nt].v, acc[kt][nt], 0, 0, 0);
    }
    __syncthreads();   // all s=0 reads done (rows 0..127)

    // s=0 epilogue: write rows 0..127 in place (disjoint from s=1's reads)
    #pragma unroll
    for (int kt = 0; kt < 4; ++kt) {
      int col = ((wk * 4 + kt) * 16 + g * 4) ^ cs;
      #pragma unroll
      for (int nt = 0; nt < 4; ++nt) {
        int row = wn * 64 + nt * 16 + c;
        f32x4 v = __builtin_elementwise_max(acc[kt][nt], zf);
        BF4 b; b.v = __builtin_convertvector(v, bf16x4);
        *(uint2*)&hbuf[row * HDIM + col] = b.u2;
      }
    }

    // ---- s = 1: compute rows 128..255 ----
    #pragma unroll
    for (int kt = 0; kt < 4; ++kt)
      #pragma unroll
      for (int nt = 0; nt < 4; ++nt)
        acc[kt][nt] = bs[kt];
    #pragma unroll
    for (int kc = 0; kc < 4; ++kc) {
      BF8 bf[4];
      #pragma unroll
      for (int nt = 0; nt < 4; ++nt)
        bf[nt].v = *(const bf16x8*)&hbuf[(128 + wn * 64 + nt * 16 + c) * HDIM + ((kc * 32 + g * 8) ^ cs)];
      #pragma unroll
      for (int kt = 0; kt < 4; ++kt)
        #pragma unroll
        for (int nt = 0; nt < 4; ++nt)
          acc[kt][nt] = __builtin_amdgcn_mfma_f32_16x16x32_bf16(afb[cur][kt][kc].v, bf[nt].v, acc[kt][nt], 0, 0, 0);
    }
    __syncthreads();   // all s=1 reads done (rows 128..255)

    // s=1 epilogue: write rows 128..255 in place
    #pragma unroll
    for (int kt = 0; kt < 4; ++kt) {
      int col = ((wk * 4 + kt) * 16 + g * 4) ^ cs;
      #pragma unroll
      for (int nt = 0; nt < 4; ++nt) {
        int row = 128 + wn * 64 + nt * 16 + c;
        f32x4 v = __builtin_elementwise_max(acc[kt][nt], zf);
        BF4 b; b.v = __builtin_convertvector(v, bf16x4);
        *(uint2*)&hbuf[row * HDIM + col] = b.u2;
      }
    }
  }
  __syncthreads();   // s=1 epilogue of layer 3 visible before head reads

  // ---------------- heads: mu (D row 0) and log-sigma (D row 1) ------------
  {
    float bm  = bmu[m];
    float bsv = bsg[m];
    f32x4 acc2[2][2];   // [subtile][nt]
    #pragma unroll
    for (int s = 0; s < 2; ++s)
      #pragma unroll
      for (int nt = 0; nt < 2; ++nt) {
        acc2[s][nt] = zf;
        acc2[s][nt][0] = bm;
        acc2[s][nt][1] = bsv;
      }
    #pragma unroll
    for (int kc = 0; kc < 4; ++kc) {
      BF8 hw;
      if (c < 2) {
        const unsigned short* wp = ws + (c == 0 ? WMU_OFF : WSG_OFF) + m * HDIM + kc * 32 + g * 8;
        hw.v = *(const bf16x8*)wp;
      } else {
        hw.ui[0] = 0u; hw.ui[1] = 0u; hw.ui[2] = 0u; hw.ui[3] = 0u;
      }
      #pragma unroll
      for (int s = 0; s < 2; ++s)
        #pragma unroll
        for (int nt = 0; nt < 2; ++nt) {
          int nl = s * 128 + (wv * 2 + nt) * 16 + c;
          BF8 hf; hf.v = *(const bf16x8*)&hbuf[nl * HDIM + ((kc * 32 + g * 8) ^ cs)];
          acc2[s][nt] = __builtin_amdgcn_mfma_f32_16x16x32_bf16(hw.v, hf.v, acc2[s][nt], 0, 0, 0);
        }
    }
    if (g == 0) {
      #pragma unroll
      for (int s = 0; s < 2; ++s)
        #pragma unroll
        for (int nt = 0; nt < 2; ++nt) {
          int n = n0 + s * 128 + (wv * 2 + nt) * 16 + c;
          out[m * NPT + n]          = acc2[s][nt][0];
          out[SG_OFF + m * NPT + n] = expf(acc2[s][nt][1]);
        }
    }
  }
}

extern "C" void kernel_launch(void* const* d_in, const int* in_sizes, int n_in,
                              void* d_out, int out_size, void* d_ws, size_t ws_size,
                              hipStream_t stream) {
  const float* x   = (const float*)d_in[0];
  const float* W1  = (const float*)d_in[1];
  const float* b1  = (const float*)d_in[2];
  const float* Wh  = (const float*)d_in[3];
  const float* bh  = (const float*)d_in[4];
  const float* Wmu = (const float*)d_in[5];
  const float* bmu = (const float*)d_in[6];
  const float* Wsg = (const float*)d_in[7];
  const float* bsg = (const float*)d_in[8];
  unsigned short* ws = (unsigned short*)d_ws;
  (void)in_sizes; (void)n_in; (void)out_size; (void)ws_size;

  cvt_weights<<<(GTOT + 255) / 256, 256, 0, stream>>>(x, W1, Wh, Wmu, Wsg, ws);
  ens_mlp<<<6400, 256, 0, stream>>>(ws, b1, bh, bmu, bsg, (float*)d_out);
}